// Round 6
// baseline (279.522 us; speedup 1.0000x reference)
//
#include <hip/hip_runtime.h>
#include <hip/hip_bf16.h>
#include <math.h>

// Problem constants
#define BATCH 8
#define NSEQ  1024
#define DIMM  768
#define NHEAD 12
#define DHEAD 64
#define SCALE 0.125f           // DHEAD^-0.5
#define ROWS  (BATCH * NSEQ)   // 8192
#define LOG2E 1.44269504f
#define SCALE_L2E (0.125f * 1.44269504f)

typedef __hip_bfloat16 bf16;
typedef __bf16 bf16x8 __attribute__((ext_vector_type(8)));
typedef float  f32x4  __attribute__((ext_vector_type(4)));

#if __has_builtin(__builtin_amdgcn_global_load_lds)
#define HAVE_GLL 1
typedef __attribute__((address_space(3))) void lds_void_t;
typedef const __attribute__((address_space(1))) void gbl_void_t;
__device__ __forceinline__ void gload16(const void* g, void* l) {
    __builtin_amdgcn_global_load_lds((gbl_void_t*)g, (lds_void_t*)l, 16, 0, 0);
}
#else
#define HAVE_GLL 0
#endif

__device__ __forceinline__ unsigned pk2(float a, float b) {
    union { unsigned u; bf16 h[2]; } x;
    x.h[0] = __float2bfloat16(a);
    x.h[1] = __float2bfloat16(b);
    return x.u;
}

// ---------------------------------------------------------------- LayerNorm (fp32 in, bf16 out)
__global__ __launch_bounds__(256) void ln_kernel(const float* __restrict__ x,
                                                 const float* __restrict__ g,
                                                 const float* __restrict__ bta,
                                                 bf16* __restrict__ y) {
    __shared__ float ps[4], pq[4];
    __shared__ float mean_s, rstd_s;
    int row = blockIdx.x;
    int tid = threadIdx.x;
    const float* xr = x + (size_t)row * DIMM;
    float v[3];
    float s = 0.f, sq = 0.f;
#pragma unroll
    for (int i = 0; i < 3; ++i) {
        v[i] = xr[tid + 256 * i];
        s += v[i];
        sq += v[i] * v[i];
    }
#pragma unroll
    for (int off = 32; off >= 1; off >>= 1) {
        s  += __shfl_down(s, off);
        sq += __shfl_down(sq, off);
    }
    int wid = tid >> 6, lane = tid & 63;
    if (lane == 0) { ps[wid] = s; pq[wid] = sq; }
    __syncthreads();
    if (tid == 0) {
        float S = ps[0] + ps[1] + ps[2] + ps[3];
        float Q = pq[0] + pq[1] + pq[2] + pq[3];
        float mean = S * (1.0f / DIMM);
        float var  = Q * (1.0f / DIMM) - mean * mean;
        mean_s = mean;
        rstd_s = rsqrtf(fmaxf(var, 0.f) + 1e-5f);
    }
    __syncthreads();
    float mean = mean_s, rstd = rstd_s;
    bf16* yr = y + (size_t)row * DIMM;
#pragma unroll
    for (int i = 0; i < 3; ++i) {
        int c = tid + 256 * i;
        yr[c] = __float2bfloat16((v[i] - mean) * rstd * g[c] + bta[c]);
    }
}

// ------------------------------------------- transpose + fp32->bf16: Wt[n][k] = W[k][n]
__global__ __launch_bounds__(256) void transpose_bf16(const float* __restrict__ W,
                                                      bf16* __restrict__ Wt,
                                                      int K, int N) {
    __shared__ float t[32][33];
    int n0 = blockIdx.x * 32, k0 = blockIdx.y * 32;
    int tx = threadIdx.x, ty = threadIdx.y;   // 32, 8
#pragma unroll
    for (int i = 0; i < 32; i += 8)
        t[ty + i][tx] = W[(size_t)(k0 + ty + i) * N + n0 + tx];
    __syncthreads();
#pragma unroll
    for (int i = 0; i < 32; i += 8)
        Wt[(size_t)(n0 + ty + i) * K + k0 + tx] = __float2bfloat16(t[tx][ty + i]);
}

// ------------------------------- bf16 MFMA GEMM (T4: counted vmcnt, depth-2 prefetch)
// C[M,Nn] = A[M,K] @ Bt[Nn,K]^T (+bias). 128x128 tile, BK=32, 3 LDS buffers.
// Steady state: 8 gloads in flight; each iter waits vmcnt(4) (tile t's loads only,
// NEVER 0), raw s_barrier (no compiler drain), stages tile t+2 into buf (t+2)%3.
// Safety: after iter-t barrier all waves consumed their iter-(t-1) ds_reads
// (lgkm enforced before their MFMAs), so overwriting buf (t-1)%3 == (t+2)%3 is safe.
template <bool OUT_BF16>
__global__ __launch_bounds__(256) void gemm_mfma(const bf16* __restrict__ A,
                                                 const bf16* __restrict__ Bt,
                                                 const float* __restrict__ bias,
                                                 void* __restrict__ Cv,
                                                 int M, int Nn, int K) {
    __shared__ bf16 As[3][128][32];   // unpadded: lane-linear for global_load_lds
    __shared__ bf16 Bs[3][128][32];   // 48 KB total -> 3 blocks/CU
    int tid = threadIdx.x;
    int wave = tid >> 6, lane = tid & 63, quad = lane >> 4, l16 = lane & 15;
    int wm = (wave >> 1) * 64, wn = (wave & 1) * 64;
    int m0 = blockIdx.y * 128, n0 = blockIdx.x * 128;

    f32x4 acc[4][4] = {};

#if HAVE_GLL
    const char* Ag = (const char*)(A  + (size_t)(m0 + (tid >> 2)) * K + (tid & 3) * 8);
    const char* Bg = (const char*)(Bt + (size_t)(n0 + (tid >> 2)) * K + (tid & 3) * 8);
    char* AsB = (char*)&As[0][0][0] + tid * 16;
    char* BsB = (char*)&Bs[0][0][0] + tid * 16;
    const size_t radv = (size_t)64 * K * 2;   // +64 rows

    const int nt = K >> 5;
    // prologue: tile 0 -> buf 0, tile 1 -> buf 1  (8 loads in flight)
    gload16(Ag, AsB);        gload16(Ag + radv, AsB + 4096);
    gload16(Bg, BsB);        gload16(Bg + radv, BsB + 4096);
    Ag += 64; Bg += 64;
    gload16(Ag, AsB + 8192); gload16(Ag + radv, AsB + 8192 + 4096);
    gload16(Bg, BsB + 8192); gload16(Bg + radv, BsB + 8192 + 4096);
    Ag += 64; Bg += 64;

    int cur = 0, st = 2;    // buf of tile t; buf for tile t+2
    for (int t = 0; t < nt; ++t) {
        if (t + 1 < nt) { asm volatile("s_waitcnt vmcnt(4)" ::: "memory"); }
        else            { asm volatile("s_waitcnt vmcnt(0)" ::: "memory"); }
        __builtin_amdgcn_s_barrier();
        __builtin_amdgcn_sched_barrier(0);
        if (t + 2 < nt) {   // stage tile t+2 (async) while computing tile t
            char* ad = AsB + st * 8192;
            char* bd = BsB + st * 8192;
            gload16(Ag, ad); gload16(Ag + radv, ad + 4096);
            gload16(Bg, bd); gload16(Bg + radv, bd + 4096);
            Ag += 64; Bg += 64;
        }
        bf16x8 af[4], bf_[4];
#pragma unroll
        for (int i = 0; i < 4; ++i) {
            af[i]  = *(const bf16x8*)&As[cur][wm + i * 16 + l16][quad * 8];
            bf_[i] = *(const bf16x8*)&Bs[cur][wn + i * 16 + l16][quad * 8];
        }
#pragma unroll
        for (int mi = 0; mi < 4; ++mi)
#pragma unroll
            for (int ni = 0; ni < 4; ++ni)
                acc[mi][ni] = __builtin_amdgcn_mfma_f32_16x16x32_bf16(
                    af[mi], bf_[ni], acc[mi][ni], 0, 0, 0);
        cur = (cur + 1 == 3) ? 0 : cur + 1;
        st  = (st  + 1 == 3) ? 0 : st  + 1;
    }
#else
    int srow = tid >> 1;
    int sk = (tid & 1) * 16;
    const bf16* Ap = A  + (size_t)(m0 + srow) * K + sk;
    const bf16* Bp = Bt + (size_t)(n0 + srow) * K + sk;
    // fallback: 2-buffer dbuf with __syncthreads (bufs 0/1)
    {
        uint4 a0 = *(const uint4*)(Ap);
        uint4 a1 = *(const uint4*)(Ap + 8);
        uint4 b0 = *(const uint4*)(Bp);
        uint4 b1 = *(const uint4*)(Bp + 8);
        *(uint4*)&As[0][srow][sk]     = a0;
        *(uint4*)&As[0][srow][sk + 8] = a1;
        *(uint4*)&Bs[0][srow][sk]     = b0;
        *(uint4*)&Bs[0][srow][sk + 8] = b1;
    }
    __syncthreads();
    int cur = 0;
    for (int k0 = 0; k0 < K; k0 += 32) {
        int nxt = cur ^ 1;
        uint4 a0, a1, b0, b1;
        if (k0 + 32 < K) {
            a0 = *(const uint4*)(Ap + k0 + 32);
            a1 = *(const uint4*)(Ap + k0 + 40);
            b0 = *(const uint4*)(Bp + k0 + 32);
            b1 = *(const uint4*)(Bp + k0 + 40);
        }
        bf16x8 af[4], bf_[4];
#pragma unroll
        for (int i = 0; i < 4; ++i) {
            af[i]  = *(const bf16x8*)&As[cur][wm + i * 16 + l16][quad * 8];
            bf_[i] = *(const bf16x8*)&Bs[cur][wn + i * 16 + l16][quad * 8];
        }
#pragma unroll
        for (int mi = 0; mi < 4; ++mi)
#pragma unroll
            for (int ni = 0; ni < 4; ++ni)
                acc[mi][ni] = __builtin_amdgcn_mfma_f32_16x16x32_bf16(
                    af[mi], bf_[ni], acc[mi][ni], 0, 0, 0);
        if (k0 + 32 < K) {
            *(uint4*)&As[nxt][srow][sk]     = a0;
            *(uint4*)&As[nxt][srow][sk + 8] = a1;
            *(uint4*)&Bs[nxt][srow][sk]     = b0;
            *(uint4*)&Bs[nxt][srow][sk + 8] = b1;
        }
        __syncthreads();
        cur = nxt;
    }
#endif

    float bv[4] = {0.f, 0.f, 0.f, 0.f};
    if (!OUT_BF16 && bias) {
#pragma unroll
        for (int ni = 0; ni < 4; ++ni) bv[ni] = bias[n0 + wn + ni * 16 + l16];
    }
#pragma unroll
    for (int mi = 0; mi < 4; ++mi)
#pragma unroll
        for (int reg = 0; reg < 4; ++reg) {
            size_t row = m0 + wm + mi * 16 + quad * 4 + reg;
#pragma unroll
            for (int ni = 0; ni < 4; ++ni) {
                int col = n0 + wn + ni * 16 + l16;
                float val = acc[mi][ni][reg] + bv[ni];
                if (OUT_BF16)
                    ((bf16*)Cv)[row * Nn + col] = __float2bfloat16(val);
                else
                    ((float*)Cv)[row * Nn + col] = val;
            }
        }
}

// ------------------------------------------------- MFMA flash attention (S^T form, dbuf)
// R4 structure (proven 95 us): K dbuf via global_load_lds, V dbuf transposed+swizzled,
// ONE __syncthreads per tile. Log2-domain softmax kept from R5 (verified numerics):
// rpb pre-scaled by log2e at prefetch, SCALE*log2e in the fmaf, native exp2f.
// rpb prefetch one tile ahead; bijective XCD swizzle; setprio; T13 defer (THR=11.5 lg2).
// qkv: [ROWS, 2304] bf16. rpb: [NHEAD, NSEQ, NSEQ] fp32. outb: [ROWS, DIMM] bf16.
#define KTILEB (64 * 3 * DIMM * 2)   // bytes per 64-row k-tile step in qkv
#define NBLK   (BATCH * NHEAD * (NSEQ / 64))   // 1536

__global__ __launch_bounds__(256, 4) void attn_mfma(const bf16* __restrict__ qkv,
                                                    const float* __restrict__ rpb,
                                                    bf16* __restrict__ outb) {
    __shared__ char KsRaw[2][8192];     // [buf][t*2048 + s*1024 + (quad*16+l16)*16]
    __shared__ unsigned Vt32[2][64][36];// [buf][d][k-pair dword], XOR-swizzled blocks
    __shared__ bf16 Ps[4][16][72];      // per-wave P (A-layout): row q, col k

    int tid = threadIdx.x;
    int wave = tid >> 6, lane = tid & 63, quad = lane >> 4, l16 = lane & 15;

    // Locality-ordered bijective XCD swizzle (NBLK=1536, 1536%8==0)
    int p   = blockIdx.x;
    int wid = (p & 7) * (NBLK / 8) + (p >> 3);
    int h   = wid >> 7;          // wid / 128
    int rem = wid & 127;
    int b   = rem >> 4;
    int mt  = rem & 15;
    int m0  = mt * 64;

    // Q B-fragments in registers (wave owns q rows wave*16..+16; n-index = l16)
    const bf16* qrow = qkv + (size_t)(b * NSEQ + m0 + wave * 16 + l16) * (3 * DIMM) + h * DHEAD;
    bf16x8 qf0 = *(const bf16x8*)(qrow + quad * 8);
    bf16x8 qf1 = *(const bf16x8*)(qrow + 32 + quad * 8);

    // rpb row for this lane's q (= l16)
    const float* rp = rpb + ((size_t)h * NSEQ + (m0 + wave * 16 + l16)) * NSEQ;

#if HAVE_GLL
    // K staging: wave w stages k-subtile t=w, rows w*16+l16, col chunk quad*8 (+i*32)
    const char* kgl = (const char*)(qkv + (size_t)(b * NSEQ + wave * 16 + l16) * (3 * DIMM)
                                    + DIMM + h * DHEAD + quad * 8);
    char* kdst = &KsRaw[0][0] + tid * 16 + wave * 1024;   // +buf*8192, +i*1024
#else
    // fallback: coalesced reg staging (row tid>>2, 16-col chunk (tid&3)*16)
    int ksr = tid >> 2, ksd = (tid & 3) * 16;
    const bf16* kgf = qkv + (size_t)(b * NSEQ + ksr) * (3 * DIMM) + DIMM + h * DHEAD + ksd;
#endif

    // V loader: thread owns 2 adjacent k-rows x 8 d-cols
    int vk = (tid >> 3) * 2;            // 0..62 even
    int vd = (tid & 7) * 8;             // 0..56
    int vkp = tid >> 3;                 // logical dword col (k-pair)
    const bf16* vg = qkv + (size_t)(b * NSEQ + vk) * (3 * DIMM) + 2 * DIMM + h * DHEAD + vd;
    int wblk = (((vkp >> 2) ^ (vd >> 3)) << 2) | (vkp & 3);

    float m_s = -INFINITY, l_s = 0.f;   // m_s in log2 units
    f32x4 acco[4] = {};

    // ---------------- preload tile 0
#if HAVE_GLL
    gload16(kgl, kdst);
    gload16(kgl + 64, kdst + 1024);
#endif
    uint4 va = *(const uint4*)(vg);
    uint4 vb = *(const uint4*)(vg + 3 * DIMM);
#if !HAVE_GLL
    {
        uint4 k0v = *(const uint4*)(kgf);
        uint4 k1v = *(const uint4*)(kgf + 8);
        char* d0 = &KsRaw[0][0] + (ksr >> 4) * 2048 + (ksd >> 5) * 1024 + ((((ksd >> 3) & 3) * 16 + (ksr & 15)) * 16);
        *(uint4*)d0 = k0v;
        char* d1 = &KsRaw[0][0] + (ksr >> 4) * 2048 + ((ksd + 8) >> 5) * 1024 + (((((ksd + 8) >> 3) & 3) * 16 + (ksr & 15)) * 16);
        *(uint4*)d1 = k1v;
    }
#endif
    {
        union { uint4 q; unsigned short u[8]; } A_, B_;
        A_.q = va; B_.q = vb;
#pragma unroll
        for (int j = 0; j < 8; ++j)
            Vt32[0][vd + j][wblk] = (unsigned)A_.u[j] | ((unsigned)B_.u[j] << 16);
    }
    // rpb tile 0 preload (registers), pre-scaled to log2 domain
    float4 rv[4];
#pragma unroll
    for (int t = 0; t < 4; ++t) {
        float4 r = *(const float4*)&rp[t * 16 + quad * 4];
        rv[t] = make_float4(r.x * LOG2E, r.y * LOG2E, r.z * LOG2E, r.w * LOG2E);
    }
    __syncthreads();   // drains gll vmcnt + ds writes

    for (int kt = 0; kt < 16; ++kt) {
        int cur = kt & 1, nxt = cur ^ 1;

        // ---- prefetch next tile (K -> LDS[nxt] async, V -> regs, rpb -> regs)
        float4 rvn[4];
        if (kt + 1 < 16) {
#if HAVE_GLL
            const char* kg2 = kgl + (size_t)(kt + 1) * KTILEB;
            gload16(kg2, kdst + nxt * 8192);
            gload16(kg2 + 64, kdst + nxt * 8192 + 1024);
#endif
            const bf16* v2 = vg + (size_t)(kt + 1) * 64 * (3 * DIMM);
            va = *(const uint4*)(v2);
            vb = *(const uint4*)(v2 + 3 * DIMM);
            const float* rpn = rp + (kt + 1) * 64;
#pragma unroll
            for (int t = 0; t < 4; ++t) {
                float4 r = *(const float4*)&rpn[t * 16 + quad * 4];
                rvn[t] = make_float4(r.x * LOG2E, r.y * LOG2E, r.z * LOG2E, r.w * LOG2E);
            }
        }

        // ---- S^T = K Q^T : accs[t][r] = S[q=l16][k = kt*64 + t*16 + quad*4 + r]
        f32x4 accs[4] = {};
        __builtin_amdgcn_s_setprio(1);
#pragma unroll
        for (int t = 0; t < 4; ++t) {
            const char* kb = &KsRaw[cur][0] + t * 2048 + (quad * 16 + l16) * 16;
            bf16x8 kf0 = *(const bf16x8*)(kb);
            bf16x8 kf1 = *(const bf16x8*)(kb + 1024);
            accs[t] = __builtin_amdgcn_mfma_f32_16x16x32_bf16(kf0, qf0, accs[t], 0, 0, 0);
            accs[t] = __builtin_amdgcn_mfma_f32_16x16x32_bf16(kf1, qf1, accs[t], 0, 0, 0);
        }
        __builtin_amdgcn_s_setprio(0);

        // ---- softmax over k, log2 domain (in-register + 2 shuffles across quads)
        float mx = -INFINITY;
        {
            float rb[4][4] = {{rv[0].x, rv[0].y, rv[0].z, rv[0].w},
                              {rv[1].x, rv[1].y, rv[1].z, rv[1].w},
                              {rv[2].x, rv[2].y, rv[2].z, rv[2].w},
                              {rv[3].x, rv[3].y, rv[3].z, rv[3].w}};
#pragma unroll
            for (int t = 0; t < 4; ++t)
#pragma unroll
                for (int r = 0; r < 4; ++r) {
                    accs[t][r] = fmaf(accs[t][r], SCALE_L2E, rb[t][r]);
                    mx = fmaxf(mx, accs[t][r]);
                }
        }
        mx = fmaxf(mx, __shfl_xor(mx, 16));
        mx = fmaxf(mx, __shfl_xor(mx, 32));

        // ---- T13 defer-rescale (THR = 11.5 log2-units ~= 8 nats)
        if (__any(mx > m_s + 11.5f)) {
            float mn = fmaxf(m_s, mx);
            float alpha = exp2f(m_s - mn);
            m_s = mn;
            l_s *= alpha;
            float ab[4];
#pragma unroll
            for (int r = 0; r < 4; ++r) ab[r] = __shfl(alpha, quad * 4 + r);
#pragma unroll
            for (int dt = 0; dt < 4; ++dt)
#pragma unroll
                for (int r = 0; r < 4; ++r) acco[dt][r] *= ab[r];
        }

        float sum = 0.f;
#pragma unroll
        for (int t = 0; t < 4; ++t)
#pragma unroll
            for (int r = 0; r < 4; ++r) {
                float pv = exp2f(accs[t][r] - m_s);
                accs[t][r] = pv;
                sum += pv;
            }
        sum += __shfl_xor(sum, 16);
        sum += __shfl_xor(sum, 32);
        l_s += sum;

        // ---- P^T -> Ps (A-layout): row q=l16, cols k (4 consecutive per lane per t)
#pragma unroll
        for (int t = 0; t < 4; ++t) {
            uint2 w;
            w.x = pk2(accs[t][0], accs[t][1]);
            w.y = pk2(accs[t][2], accs[t][3]);
            *(uint2*)&Ps[wave][l16][t * 16 + quad * 4] = w;
        }
        __asm__ volatile("s_waitcnt lgkmcnt(0)" ::: "memory");

        // ---- O += P V  (A=P-frag from Ps, B=V^T-frag from swizzled Vt[cur])
        __builtin_amdgcn_s_setprio(1);
#pragma unroll
        for (int s = 0; s < 2; ++s) {
            bf16x8 pf = *(const bf16x8*)&Ps[wave][l16][s * 32 + quad * 8];
#pragma unroll
            for (int dt = 0; dt < 4; ++dt) {
                int row = dt * 16 + l16;
                int sblk = (((s * 4 + quad) ^ ((row >> 3) & 7)) << 2);
                bf16x8 vf = *(const bf16x8*)&Vt32[cur][row][sblk];
                acco[dt] = __builtin_amdgcn_mfma_f32_16x16x32_bf16(pf, vf, acco[dt], 0, 0, 0);
            }
        }
        __builtin_amdgcn_s_setprio(0);

        // ---- stage prefetched V into Vt[nxt]; rotate rpb regs
        if (kt + 1 < 16) {
            union { uint4 q; unsigned short u[8]; } A_, B_;
            A_.q = va; B_.q = vb;
#pragma unroll
            for (int j = 0; j < 8; ++j)
                Vt32[nxt][vd + j][wblk] = (unsigned)A_.u[j] | ((unsigned)B_.u[j] << 16);
#pragma unroll
            for (int t = 0; t < 4; ++t) rv[t] = rvn[t];
        }
        __syncthreads();   // K[nxt] gll drained; V[nxt] visible; cur reads done
    }

    // ---- epilogue: O / l (l for q=quad*4+r via shuffle), bf16 store
    float invl[4];
#pragma unroll
    for (int r = 0; r < 4; ++r) invl[r] = 1.f / __shfl(l_s, quad * 4 + r);
    bf16* orow = outb + (size_t)(b * NSEQ + m0 + wave * 16) * DIMM + h * DHEAD;
#pragma unroll
    for (int dt = 0; dt < 4; ++dt)
#pragma unroll
        for (int r = 0; r < 4; ++r)
            orow[(size_t)(quad * 4 + r) * DIMM + dt * 16 + l16] =
                __float2bfloat16(acco[dt][r] * invl[r]);
}

// ---------------------------------------------------------------- launch
extern "C" void kernel_launch(void* const* d_in, const int* in_sizes, int n_in,
                              void* d_out, int out_size, void* d_ws, size_t ws_size,
                              hipStream_t stream) {
    const float* x     = (const float*)d_in[0];
    const float* rpb   = (const float*)d_in[1];
    const float* W_qkv = (const float*)d_in[2];
    const float* W_out = (const float*)d_in[3];
    const float* b_out = (const float*)d_in[4];
    const float* ln_g  = (const float*)d_in[5];
    const float* ln_b  = (const float*)d_in[6];
    float* out = (float*)d_out;

    char* p = (char*)d_ws;
    bf16* xn    = (bf16*)p; p += (size_t)ROWS * DIMM * 2;
    bf16* qkv   = (bf16*)p; p += (size_t)ROWS * 3 * DIMM * 2;
    bf16* attn  = (bf16*)p; p += (size_t)ROWS * DIMM * 2;
    bf16* WqkvT = (bf16*)p; p += (size_t)3 * DIMM * DIMM * 2;
    bf16* WoutT = (bf16*)p; p += (size_t)DIMM * DIMM * 2;

    ln_kernel<<<ROWS, 256, 0, stream>>>(x, ln_g, ln_b, xn);
    transpose_bf16<<<dim3(3 * DIMM / 32, DIMM / 32), dim3(32, 8), 0, stream>>>(
        W_qkv, WqkvT, DIMM, 3 * DIMM);
    transpose_bf16<<<dim3(DIMM / 32, DIMM / 32), dim3(32, 8), 0, stream>>>(
        W_out, WoutT, DIMM, DIMM);

    gemm_mfma<true><<<dim3(3 * DIMM / 128, ROWS / 128), 256, 0, stream>>>(
        xn, WqkvT, nullptr, qkv, ROWS, 3 * DIMM, DIMM);

    attn_mfma<<<NBLK, 256, 0, stream>>>(qkv, rpb, attn);

    gemm_mfma<false><<<dim3(DIMM / 128, ROWS / 128), 256, 0, stream>>>(
        attn, WoutT, b_out, out, ROWS, DIMM, DIMM);
}

// Round 7
// 265.959 us; speedup vs baseline: 1.0510x; 1.0510x over previous
//
#include <hip/hip_runtime.h>
#include <hip/hip_bf16.h>
#include <math.h>

// Problem constants
#define BATCH 8
#define NSEQ  1024
#define DIMM  768
#define NHEAD 12
#define DHEAD 64
#define SCALE 0.125f           // DHEAD^-0.5
#define ROWS  (BATCH * NSEQ)   // 8192

typedef __hip_bfloat16 bf16;
typedef __bf16 bf16x8 __attribute__((ext_vector_type(8)));
typedef float  f32x4  __attribute__((ext_vector_type(4)));

#if __has_builtin(__builtin_amdgcn_global_load_lds)
#define HAVE_GLL 1
typedef __attribute__((address_space(3))) void lds_void_t;
typedef const __attribute__((address_space(1))) void gbl_void_t;
__device__ __forceinline__ void gload16(const void* g, void* l) {
    __builtin_amdgcn_global_load_lds((gbl_void_t*)g, (lds_void_t*)l, 16, 0, 0);
}
#else
#define HAVE_GLL 0
#endif

__device__ __forceinline__ unsigned pk2(float a, float b) {
    union { unsigned u; bf16 h[2]; } x;
    x.h[0] = __float2bfloat16(a);
    x.h[1] = __float2bfloat16(b);
    return x.u;
}

// -------------------------------------------------- fused prep: LN + 2 weight transposes
// Block-uniform branch on blockIdx.x:
//   [0, ROWS)                : LayerNorm row (fp32 in, bf16 out)
//   [ROWS, ROWS+1728)        : W_qkv transpose tile (768x2304 -> bf16 [2304][768])
//   [ROWS+1728, ROWS+2304)   : W_out transpose tile (768x768  -> bf16 [768][768])
// Interior __syncthreads are legal: the branch is uniform within a block.
#define NT_QKV (DIMM / 32 * (3 * DIMM) / 32)   // 24*72 = 1728
#define NT_OUT (DIMM / 32 * DIMM / 32)         // 24*24 = 576

__device__ __forceinline__ void transpose_tile(const float* __restrict__ W,
                                               bf16* __restrict__ Wt,
                                               int K, int N, int n0, int k0,
                                               int tx, int ty, float (*t)[33]) {
#pragma unroll
    for (int i = 0; i < 32; i += 8)
        t[ty + i][tx] = W[(size_t)(k0 + ty + i) * N + n0 + tx];
    __syncthreads();
#pragma unroll
    for (int i = 0; i < 32; i += 8)
        Wt[(size_t)(n0 + ty + i) * K + k0 + tx] = __float2bfloat16(t[tx][ty + i]);
}

__global__ __launch_bounds__(256) void prep_kernel(const float* __restrict__ x,
                                                   const float* __restrict__ g,
                                                   const float* __restrict__ bta,
                                                   bf16* __restrict__ y,
                                                   const float* __restrict__ Wq,
                                                   bf16* __restrict__ WqT,
                                                   const float* __restrict__ Wo,
                                                   bf16* __restrict__ WoT) {
    __shared__ float ps[4], pq[4];
    __shared__ float mean_s, rstd_s;
    __shared__ float t[32][33];
    int bid = blockIdx.x;
    int tid = threadIdx.x;

    if (bid < ROWS) {
        // ---------------- LayerNorm
        const float* xr = x + (size_t)bid * DIMM;
        float v[3];
        float s = 0.f, sq = 0.f;
#pragma unroll
        for (int i = 0; i < 3; ++i) {
            v[i] = xr[tid + 256 * i];
            s += v[i];
            sq += v[i] * v[i];
        }
#pragma unroll
        for (int off = 32; off >= 1; off >>= 1) {
            s  += __shfl_down(s, off);
            sq += __shfl_down(sq, off);
        }
        int wid = tid >> 6, lane = tid & 63;
        if (lane == 0) { ps[wid] = s; pq[wid] = sq; }
        __syncthreads();
        if (tid == 0) {
            float S = ps[0] + ps[1] + ps[2] + ps[3];
            float Q = pq[0] + pq[1] + pq[2] + pq[3];
            float mean = S * (1.0f / DIMM);
            float var  = Q * (1.0f / DIMM) - mean * mean;
            mean_s = mean;
            rstd_s = rsqrtf(fmaxf(var, 0.f) + 1e-5f);
        }
        __syncthreads();
        float mean = mean_s, rstd = rstd_s;
        bf16* yr = y + (size_t)bid * DIMM;
#pragma unroll
        for (int i = 0; i < 3; ++i) {
            int c = tid + 256 * i;
            yr[c] = __float2bfloat16((v[i] - mean) * rstd * g[c] + bta[c]);
        }
    } else if (bid < ROWS + NT_QKV) {
        int idx = bid - ROWS;
        int tx = tid & 31, ty = tid >> 5;
        int n0 = (idx % (3 * DIMM / 32)) * 32;
        int k0 = (idx / (3 * DIMM / 32)) * 32;
        transpose_tile(Wq, WqT, DIMM, 3 * DIMM, n0, k0, tx, ty, t);
    } else {
        int idx = bid - ROWS - NT_QKV;
        int tx = tid & 31, ty = tid >> 5;
        int n0 = (idx % (DIMM / 32)) * 32;
        int k0 = (idx / (DIMM / 32)) * 32;
        transpose_tile(Wo, WoT, DIMM, DIMM, n0, k0, tx, ty, t);
    }
}

// ------------------------------------------------------- bf16 MFMA GEMM (m97 + T3 dbuf)
// C[M,Nn] = A[M,K] @ Bt[Nn,K]^T (+bias). 128x128 tile, BK=32.
// T3 minimal 2-phase: STAGE(buf^1, tile t+1) via global_load_lds BEFORE computing
// buf[cur]; ONE barrier per K-iter. (R6's counted-vmcnt depth-2 was NULL -> reverted.)
template <bool OUT_BF16>
__global__ __launch_bounds__(256) void gemm_mfma(const bf16* __restrict__ A,
                                                 const bf16* __restrict__ Bt,
                                                 const float* __restrict__ bias,
                                                 void* __restrict__ Cv,
                                                 int M, int Nn, int K) {
    __shared__ bf16 As[2][128][32];   // unpadded: lane-linear for global_load_lds
    __shared__ bf16 Bs[2][128][32];   // 32 KB total
    int tid = threadIdx.x;
    int wave = tid >> 6, lane = tid & 63, quad = lane >> 4, l16 = lane & 15;
    int wm = (wave >> 1) * 64, wn = (wave & 1) * 64;
    int m0 = blockIdx.y * 128, n0 = blockIdx.x * 128;

    f32x4 acc[4][4] = {};

#if HAVE_GLL
    const char* Ag = (const char*)(A  + (size_t)(m0 + (tid >> 2)) * K + (tid & 3) * 8);
    const char* Bg = (const char*)(Bt + (size_t)(n0 + (tid >> 2)) * K + (tid & 3) * 8);
    char* AsB = (char*)&As[0][0][0] + tid * 16;
    char* BsB = (char*)&Bs[0][0][0] + tid * 16;
    const size_t radv = (size_t)64 * K * 2;   // +64 rows

    // prologue: stage tile 0 into buf 0
    gload16(Ag, AsB);
    gload16(Ag + radv, AsB + 4096);
    gload16(Bg, BsB);
    gload16(Bg + radv, BsB + 4096);
    Ag += 64; Bg += 64;               // 32 bf16
    __syncthreads();                  // drains vmcnt -> tile 0 visible

    int cur = 0;
    for (int k0 = 0; k0 < K; k0 += 32) {
        int nxt = cur ^ 1;
        // ---- stage NEXT tile (async) while computing CURRENT
        if (k0 + 32 < K) {
            gload16(Ag, AsB + nxt * 8192);
            gload16(Ag + radv, AsB + nxt * 8192 + 4096);
            gload16(Bg, BsB + nxt * 8192);
            gload16(Bg + radv, BsB + nxt * 8192 + 4096);
            Ag += 64; Bg += 64;
        }
#else
    int srow = tid >> 1;
    int sk = (tid & 1) * 16;
    const bf16* Ap = A  + (size_t)(m0 + srow) * K + sk;
    const bf16* Bp = Bt + (size_t)(n0 + srow) * K + sk;
    // prologue: tile 0 -> buf 0
    {
        uint4 a0 = *(const uint4*)(Ap);
        uint4 a1 = *(const uint4*)(Ap + 8);
        uint4 b0 = *(const uint4*)(Bp);
        uint4 b1 = *(const uint4*)(Bp + 8);
        *(uint4*)&As[0][srow][sk]     = a0;
        *(uint4*)&As[0][srow][sk + 8] = a1;
        *(uint4*)&Bs[0][srow][sk]     = b0;
        *(uint4*)&Bs[0][srow][sk + 8] = b1;
    }
    __syncthreads();
    int cur = 0;
    for (int k0 = 0; k0 < K; k0 += 32) {
        int nxt = cur ^ 1;
        uint4 a0, a1, b0, b1;
        if (k0 + 32 < K) {
            a0 = *(const uint4*)(Ap + k0 + 32);
            a1 = *(const uint4*)(Ap + k0 + 40);
            b0 = *(const uint4*)(Bp + k0 + 32);
            b1 = *(const uint4*)(Bp + k0 + 40);
        }
#endif
        bf16x8 af[4], bf_[4];
#pragma unroll
        for (int i = 0; i < 4; ++i) {
            af[i]  = *(const bf16x8*)&As[cur][wm + i * 16 + l16][quad * 8];
            bf_[i] = *(const bf16x8*)&Bs[cur][wn + i * 16 + l16][quad * 8];
        }
#pragma unroll
        for (int mi = 0; mi < 4; ++mi)
#pragma unroll
            for (int ni = 0; ni < 4; ++ni)
                acc[mi][ni] = __builtin_amdgcn_mfma_f32_16x16x32_bf16(
                    af[mi], bf_[ni], acc[mi][ni], 0, 0, 0);
#if !HAVE_GLL
        if (k0 + 32 < K) {
            *(uint4*)&As[nxt][srow][sk]     = a0;
            *(uint4*)&As[nxt][srow][sk + 8] = a1;
            *(uint4*)&Bs[nxt][srow][sk]     = b0;
            *(uint4*)&Bs[nxt][srow][sk + 8] = b1;
        }
#endif
        __syncthreads();   // next-tile staging drained/visible; cur reads done
        cur = nxt;
    }

    float bv[4] = {0.f, 0.f, 0.f, 0.f};
    if (!OUT_BF16 && bias) {
#pragma unroll
        for (int ni = 0; ni < 4; ++ni) bv[ni] = bias[n0 + wn + ni * 16 + l16];
    }
#pragma unroll
    for (int mi = 0; mi < 4; ++mi)
#pragma unroll
        for (int reg = 0; reg < 4; ++reg) {
            size_t row = m0 + wm + mi * 16 + quad * 4 + reg;
#pragma unroll
            for (int ni = 0; ni < 4; ++ni) {
                int col = n0 + wn + ni * 16 + l16;
                float val = acc[mi][ni][reg] + bv[ni];
                if (OUT_BF16)
                    ((bf16*)Cv)[row * Nn + col] = __float2bfloat16(val);
                else
                    ((float*)Cv)[row * Nn + col] = val;
            }
        }
}

// ------------------------------------------------- MFMA flash attention (S^T form, dbuf)
// Byte-exact R4 structure (proven 95.4 us): K dbuf via global_load_lds, V dbuf
// transposed+swizzled, ONE __syncthreads per tile, NATURAL-exp softmax (__expf —
// the fast intrinsic; R6 proved libm exp2f costs +8 pts VALUBusy / +8 us).
// rpb prefetch one tile ahead; bijective XCD swizzle; setprio; T13 defer (THR=8).
// qkv: [ROWS, 2304] bf16. rpb: [NHEAD, NSEQ, NSEQ] fp32. outb: [ROWS, DIMM] bf16.
#define KTILEB (64 * 3 * DIMM * 2)   // bytes per 64-row k-tile step in qkv
#define NBLK   (BATCH * NHEAD * (NSEQ / 64))   // 1536

__global__ __launch_bounds__(256, 4) void attn_mfma(const bf16* __restrict__ qkv,
                                                    const float* __restrict__ rpb,
                                                    bf16* __restrict__ outb) {
    __shared__ char KsRaw[2][8192];     // [buf][t*2048 + s*1024 + (quad*16+l16)*16]
    __shared__ unsigned Vt32[2][64][36];// [buf][d][k-pair dword], XOR-swizzled blocks
    __shared__ bf16 Ps[4][16][72];      // per-wave P (A-layout): row q, col k

    int tid = threadIdx.x;
    int wave = tid >> 6, lane = tid & 63, quad = lane >> 4, l16 = lane & 15;

    // Locality-ordered bijective XCD swizzle (NBLK=1536, 1536%8==0):
    // phys p -> xcd p&7; xcd owns contiguous wid chunk [xcd*192, xcd*192+192).
    // wid order: h outer, b mid, mt inner -> 16 consecutive wids share K/V stripe.
    int p   = blockIdx.x;
    int wid = (p & 7) * (NBLK / 8) + (p >> 3);
    int h   = wid >> 7;          // wid / 128
    int rem = wid & 127;
    int b   = rem >> 4;
    int mt  = rem & 15;
    int m0  = mt * 64;

    // Q B-fragments in registers (wave owns q rows wave*16..+16; n-index = l16)
    const bf16* qrow = qkv + (size_t)(b * NSEQ + m0 + wave * 16 + l16) * (3 * DIMM) + h * DHEAD;
    bf16x8 qf0 = *(const bf16x8*)(qrow + quad * 8);
    bf16x8 qf1 = *(const bf16x8*)(qrow + 32 + quad * 8);

    // rpb row for this lane's q (= l16)
    const float* rp = rpb + ((size_t)h * NSEQ + (m0 + wave * 16 + l16)) * NSEQ;

#if HAVE_GLL
    // K staging: wave w stages k-subtile t=w, rows w*16+l16, col chunk quad*8 (+i*32)
    const char* kgl = (const char*)(qkv + (size_t)(b * NSEQ + wave * 16 + l16) * (3 * DIMM)
                                    + DIMM + h * DHEAD + quad * 8);
    char* kdst = &KsRaw[0][0] + tid * 16 + wave * 1024;   // +buf*8192, +i*1024
#else
    // fallback: coalesced reg staging (row tid>>2, 16-col chunk (tid&3)*16)
    int ksr = tid >> 2, ksd = (tid & 3) * 16;
    const bf16* kgf = qkv + (size_t)(b * NSEQ + ksr) * (3 * DIMM) + DIMM + h * DHEAD + ksd;
#endif

    // V loader: thread owns 2 adjacent k-rows x 8 d-cols
    int vk = (tid >> 3) * 2;            // 0..62 even
    int vd = (tid & 7) * 8;             // 0..56
    int vkp = tid >> 3;                 // logical dword col (k-pair)
    const bf16* vg = qkv + (size_t)(b * NSEQ + vk) * (3 * DIMM) + 2 * DIMM + h * DHEAD + vd;
    int wblk = (((vkp >> 2) ^ (vd >> 3)) << 2) | (vkp & 3);

    float m_s = -INFINITY, l_s = 0.f;
    f32x4 acco[4] = {};

    // ---------------- preload tile 0
#if HAVE_GLL
    gload16(kgl, kdst);
    gload16(kgl + 64, kdst + 1024);
#endif
    uint4 va = *(const uint4*)(vg);
    uint4 vb = *(const uint4*)(vg + 3 * DIMM);
#if !HAVE_GLL
    {
        uint4 k0v = *(const uint4*)(kgf);
        uint4 k1v = *(const uint4*)(kgf + 8);
        char* d0 = &KsRaw[0][0] + (ksr >> 4) * 2048 + (ksd >> 5) * 1024 + ((((ksd >> 3) & 3) * 16 + (ksr & 15)) * 16);
        *(uint4*)d0 = k0v;
        char* d1 = &KsRaw[0][0] + (ksr >> 4) * 2048 + ((ksd + 8) >> 5) * 1024 + (((((ksd + 8) >> 3) & 3) * 16 + (ksr & 15)) * 16);
        *(uint4*)d1 = k1v;
    }
#endif
    {
        union { uint4 q; unsigned short u[8]; } A_, B_;
        A_.q = va; B_.q = vb;
#pragma unroll
        for (int j = 0; j < 8; ++j)
            Vt32[0][vd + j][wblk] = (unsigned)A_.u[j] | ((unsigned)B_.u[j] << 16);
    }
    // rpb tile 0 preload (registers)
    float4 rv[4];
#pragma unroll
    for (int t = 0; t < 4; ++t)
        rv[t] = *(const float4*)&rp[t * 16 + quad * 4];
    __syncthreads();   // drains gll vmcnt + ds writes

    for (int kt = 0; kt < 16; ++kt) {
        int cur = kt & 1, nxt = cur ^ 1;

        // ---- prefetch next tile (K -> LDS[nxt] async, V -> regs, rpb -> regs)
        float4 rvn[4];
        if (kt + 1 < 16) {
#if HAVE_GLL
            const char* kg2 = kgl + (size_t)(kt + 1) * KTILEB;
            gload16(kg2, kdst + nxt * 8192);
            gload16(kg2 + 64, kdst + nxt * 8192 + 1024);
#endif
            const bf16* v2 = vg + (size_t)(kt + 1) * 64 * (3 * DIMM);
            va = *(const uint4*)(v2);
            vb = *(const uint4*)(v2 + 3 * DIMM);
            const float* rpn = rp + (kt + 1) * 64;
#pragma unroll
            for (int t = 0; t < 4; ++t)
                rvn[t] = *(const float4*)&rpn[t * 16 + quad * 4];
        }

        // ---- S^T = K Q^T : accs[t][r] = S[q=l16][k = kt*64 + t*16 + quad*4 + r]
        f32x4 accs[4] = {};
        __builtin_amdgcn_s_setprio(1);
#pragma unroll
        for (int t = 0; t < 4; ++t) {
            const char* kb = &KsRaw[cur][0] + t * 2048 + (quad * 16 + l16) * 16;
            bf16x8 kf0 = *(const bf16x8*)(kb);
            bf16x8 kf1 = *(const bf16x8*)(kb + 1024);
            accs[t] = __builtin_amdgcn_mfma_f32_16x16x32_bf16(kf0, qf0, accs[t], 0, 0, 0);
            accs[t] = __builtin_amdgcn_mfma_f32_16x16x32_bf16(kf1, qf1, accs[t], 0, 0, 0);
        }
        __builtin_amdgcn_s_setprio(0);

        // ---- softmax over k (in-register + 2 shuffles across quads)
        float mx = -INFINITY;
        {
            float rb[4][4] = {{rv[0].x, rv[0].y, rv[0].z, rv[0].w},
                              {rv[1].x, rv[1].y, rv[1].z, rv[1].w},
                              {rv[2].x, rv[2].y, rv[2].z, rv[2].w},
                              {rv[3].x, rv[3].y, rv[3].z, rv[3].w}};
#pragma unroll
            for (int t = 0; t < 4; ++t)
#pragma unroll
                for (int r = 0; r < 4; ++r) {
                    accs[t][r] = fmaf(accs[t][r], SCALE, rb[t][r]);
                    mx = fmaxf(mx, accs[t][r]);
                }
        }
        mx = fmaxf(mx, __shfl_xor(mx, 16));
        mx = fmaxf(mx, __shfl_xor(mx, 32));

        // ---- T13 defer-rescale: only pay alpha/shuffles/rescale when the running
        // max actually moved by > THR (wave-uniform branch; ~never on typical data).
        if (__any(mx > m_s + 8.0f)) {
            float mn = fmaxf(m_s, mx);
            float alpha = __expf(m_s - mn);
            m_s = mn;
            l_s *= alpha;
            float ab[4];
#pragma unroll
            for (int r = 0; r < 4; ++r) ab[r] = __shfl(alpha, quad * 4 + r);
#pragma unroll
            for (int dt = 0; dt < 4; ++dt)
#pragma unroll
                for (int r = 0; r < 4; ++r) acco[dt][r] *= ab[r];
        }

        float sum = 0.f;
#pragma unroll
        for (int t = 0; t < 4; ++t)
#pragma unroll
            for (int r = 0; r < 4; ++r) {
                float pv = __expf(accs[t][r] - m_s);
                accs[t][r] = pv;
                sum += pv;
            }
        sum += __shfl_xor(sum, 16);
        sum += __shfl_xor(sum, 32);
        l_s += sum;

        // ---- P^T -> Ps (A-layout): row q=l16, cols k (4 consecutive per lane per t)
#pragma unroll
        for (int t = 0; t < 4; ++t) {
            uint2 w;
            w.x = pk2(accs[t][0], accs[t][1]);
            w.y = pk2(accs[t][2], accs[t][3]);
            *(uint2*)&Ps[wave][l16][t * 16 + quad * 4] = w;
        }
        __asm__ volatile("s_waitcnt lgkmcnt(0)" ::: "memory");

        // ---- O += P V  (A=P-frag from Ps, B=V^T-frag from swizzled Vt[cur])
        __builtin_amdgcn_s_setprio(1);
#pragma unroll
        for (int s = 0; s < 2; ++s) {
            bf16x8 pf = *(const bf16x8*)&Ps[wave][l16][s * 32 + quad * 8];
#pragma unroll
            for (int dt = 0; dt < 4; ++dt) {
                int row = dt * 16 + l16;
                int sblk = (((s * 4 + quad) ^ ((row >> 3) & 7)) << 2);
                bf16x8 vf = *(const bf16x8*)&Vt32[cur][row][sblk];
                acco[dt] = __builtin_amdgcn_mfma_f32_16x16x32_bf16(pf, vf, acco[dt], 0, 0, 0);
            }
        }
        __builtin_amdgcn_s_setprio(0);

        // ---- stage prefetched V into Vt[nxt]; rotate rpb regs
        if (kt + 1 < 16) {
            union { uint4 q; unsigned short u[8]; } A_, B_;
            A_.q = va; B_.q = vb;
#pragma unroll
            for (int j = 0; j < 8; ++j)
                Vt32[nxt][vd + j][wblk] = (unsigned)A_.u[j] | ((unsigned)B_.u[j] << 16);
#pragma unroll
            for (int t = 0; t < 4; ++t) rv[t] = rvn[t];
        }
        __syncthreads();   // K[nxt] gll drained; V[nxt] visible; cur reads done
    }

    // ---- epilogue: O / l (l for q=quad*4+r via shuffle), bf16 store
    float invl[4];
#pragma unroll
    for (int r = 0; r < 4; ++r) invl[r] = 1.f / __shfl(l_s, quad * 4 + r);
    bf16* orow = outb + (size_t)(b * NSEQ + m0 + wave * 16) * DIMM + h * DHEAD;
#pragma unroll
    for (int dt = 0; dt < 4; ++dt)
#pragma unroll
        for (int r = 0; r < 4; ++r)
            orow[(size_t)(quad * 4 + r) * DIMM + dt * 16 + l16] =
                __float2bfloat16(acco[dt][r] * invl[r]);
}

// ---------------------------------------------------------------- launch
extern "C" void kernel_launch(void* const* d_in, const int* in_sizes, int n_in,
                              void* d_out, int out_size, void* d_ws, size_t ws_size,
                              hipStream_t stream) {
    const float* x     = (const float*)d_in[0];
    const float* rpb   = (const float*)d_in[1];
    const float* W_qkv = (const float*)d_in[2];
    const float* W_out = (const float*)d_in[3];
    const float* b_out = (const float*)d_in[4];
    const float* ln_g  = (const float*)d_in[5];
    const float* ln_b  = (const float*)d_in[6];
    float* out = (float*)d_out;

    char* p = (char*)d_ws;
    bf16* xn    = (bf16*)p; p += (size_t)ROWS * DIMM * 2;
    bf16* qkv   = (bf16*)p; p += (size_t)ROWS * 3 * DIMM * 2;
    bf16* attn  = (bf16*)p; p += (size_t)ROWS * DIMM * 2;
    bf16* WqkvT = (bf16*)p; p += (size_t)3 * DIMM * DIMM * 2;
    bf16* WoutT = (bf16*)p; p += (size_t)DIMM * DIMM * 2;

    prep_kernel<<<ROWS + NT_QKV + NT_OUT, 256, 0, stream>>>(
        x, ln_g, ln_b, xn, W_qkv, WqkvT, W_out, WoutT);

    gemm_mfma<true><<<dim3(3 * DIMM / 128, ROWS / 128), 256, 0, stream>>>(
        xn, WqkvT, nullptr, qkv, ROWS, 3 * DIMM, DIMM);

    attn_mfma<<<NBLK, 256, 0, stream>>>(qkv, rpb, attn);

    gemm_mfma<false><<<dim3(DIMM / 128, ROWS / 128), 256, 0, stream>>>(
        attn, WoutT, b_out, out, ROWS, DIMM, DIMM);
}

// Round 8
// 260.404 us; speedup vs baseline: 1.0734x; 1.0213x over previous
//
#include <hip/hip_runtime.h>
#include <hip/hip_bf16.h>
#include <math.h>

// Problem constants
#define BATCH 8
#define NSEQ  1024
#define DIMM  768
#define NHEAD 12
#define DHEAD 64
#define SCALE 0.125f           // DHEAD^-0.5
#define ROWS  (BATCH * NSEQ)   // 8192

typedef __hip_bfloat16 bf16;
typedef __bf16 bf16x8 __attribute__((ext_vector_type(8)));
typedef float  f32x4  __attribute__((ext_vector_type(4)));

#if __has_builtin(__builtin_amdgcn_global_load_lds)
#define HAVE_GLL 1
typedef __attribute__((address_space(3))) void lds_void_t;
typedef const __attribute__((address_space(1))) void gbl_void_t;
__device__ __forceinline__ void gload16(const void* g, void* l) {
    __builtin_amdgcn_global_load_lds((gbl_void_t*)g, (lds_void_t*)l, 16, 0, 0);
}
#else
#define HAVE_GLL 0
#endif

__device__ __forceinline__ unsigned pk2(float a, float b) {
    union { unsigned u; bf16 h[2]; } x;
    x.h[0] = __float2bfloat16(a);
    x.h[1] = __float2bfloat16(b);
    return x.u;
}

// -------------------------------------------------- fused prep: LN + 2 weight transposes
#define NT_QKV (DIMM / 32 * (3 * DIMM) / 32)   // 24*72 = 1728
#define NT_OUT (DIMM / 32 * DIMM / 32)         // 24*24 = 576

__device__ __forceinline__ void transpose_tile(const float* __restrict__ W,
                                               bf16* __restrict__ Wt,
                                               int K, int N, int n0, int k0,
                                               int tx, int ty, float (*t)[33]) {
#pragma unroll
    for (int i = 0; i < 32; i += 8)
        t[ty + i][tx] = W[(size_t)(k0 + ty + i) * N + n0 + tx];
    __syncthreads();
#pragma unroll
    for (int i = 0; i < 32; i += 8)
        Wt[(size_t)(n0 + ty + i) * K + k0 + tx] = __float2bfloat16(t[tx][ty + i]);
}

__global__ __launch_bounds__(256) void prep_kernel(const float* __restrict__ x,
                                                   const float* __restrict__ g,
                                                   const float* __restrict__ bta,
                                                   bf16* __restrict__ y,
                                                   const float* __restrict__ Wq,
                                                   bf16* __restrict__ WqT,
                                                   const float* __restrict__ Wo,
                                                   bf16* __restrict__ WoT) {
    __shared__ float ps[4], pq[4];
    __shared__ float mean_s, rstd_s;
    __shared__ float t[32][33];
    int bid = blockIdx.x;
    int tid = threadIdx.x;

    if (bid < ROWS) {
        const float* xr = x + (size_t)bid * DIMM;
        float v[3];
        float s = 0.f, sq = 0.f;
#pragma unroll
        for (int i = 0; i < 3; ++i) {
            v[i] = xr[tid + 256 * i];
            s += v[i];
            sq += v[i] * v[i];
        }
#pragma unroll
        for (int off = 32; off >= 1; off >>= 1) {
            s  += __shfl_down(s, off);
            sq += __shfl_down(sq, off);
        }
        int wid = tid >> 6, lane = tid & 63;
        if (lane == 0) { ps[wid] = s; pq[wid] = sq; }
        __syncthreads();
        if (tid == 0) {
            float S = ps[0] + ps[1] + ps[2] + ps[3];
            float Q = pq[0] + pq[1] + pq[2] + pq[3];
            float mean = S * (1.0f / DIMM);
            float var  = Q * (1.0f / DIMM) - mean * mean;
            mean_s = mean;
            rstd_s = rsqrtf(fmaxf(var, 0.f) + 1e-5f);
        }
        __syncthreads();
        float mean = mean_s, rstd = rstd_s;
        bf16* yr = y + (size_t)bid * DIMM;
#pragma unroll
        for (int i = 0; i < 3; ++i) {
            int c = tid + 256 * i;
            yr[c] = __float2bfloat16((v[i] - mean) * rstd * g[c] + bta[c]);
        }
    } else if (bid < ROWS + NT_QKV) {
        int idx = bid - ROWS;
        int tx = tid & 31, ty = tid >> 5;
        int n0 = (idx % (3 * DIMM / 32)) * 32;
        int k0 = (idx / (3 * DIMM / 32)) * 32;
        transpose_tile(Wq, WqT, DIMM, 3 * DIMM, n0, k0, tx, ty, t);
    } else {
        int idx = bid - ROWS - NT_QKV;
        int tx = tid & 31, ty = tid >> 5;
        int n0 = (idx % (DIMM / 32)) * 32;
        int k0 = (idx / (DIMM / 32)) * 32;
        transpose_tile(Wo, WoT, DIMM, DIMM, n0, k0, tx, ty, t);
    }
}

// ------------------------------------------------------- bf16 MFMA GEMM (m97 + T3 dbuf)
// C[M,Nn] = A[M,K] @ Bt[Nn,K]^T (+bias). 128x128 tile, BK=32.
// T3 minimal 2-phase: STAGE(buf^1, tile t+1) via global_load_lds BEFORE computing
// buf[cur]; ONE barrier per K-iter.
template <bool OUT_BF16>
__global__ __launch_bounds__(256) void gemm_mfma(const bf16* __restrict__ A,
                                                 const bf16* __restrict__ Bt,
                                                 const float* __restrict__ bias,
                                                 void* __restrict__ Cv,
                                                 int M, int Nn, int K) {
    __shared__ bf16 As[2][128][32];   // unpadded: lane-linear for global_load_lds
    __shared__ bf16 Bs[2][128][32];   // 32 KB total
    int tid = threadIdx.x;
    int wave = tid >> 6, lane = tid & 63, quad = lane >> 4, l16 = lane & 15;
    int wm = (wave >> 1) * 64, wn = (wave & 1) * 64;
    int m0 = blockIdx.y * 128, n0 = blockIdx.x * 128;

    f32x4 acc[4][4] = {};

#if HAVE_GLL
    const char* Ag = (const char*)(A  + (size_t)(m0 + (tid >> 2)) * K + (tid & 3) * 8);
    const char* Bg = (const char*)(Bt + (size_t)(n0 + (tid >> 2)) * K + (tid & 3) * 8);
    char* AsB = (char*)&As[0][0][0] + tid * 16;
    char* BsB = (char*)&Bs[0][0][0] + tid * 16;
    const size_t radv = (size_t)64 * K * 2;   // +64 rows

    // prologue: stage tile 0 into buf 0
    gload16(Ag, AsB);
    gload16(Ag + radv, AsB + 4096);
    gload16(Bg, BsB);
    gload16(Bg + radv, BsB + 4096);
    Ag += 64; Bg += 64;               // 32 bf16
    __syncthreads();                  // drains vmcnt -> tile 0 visible

    int cur = 0;
    for (int k0 = 0; k0 < K; k0 += 32) {
        int nxt = cur ^ 1;
        // ---- stage NEXT tile (async) while computing CURRENT
        if (k0 + 32 < K) {
            gload16(Ag, AsB + nxt * 8192);
            gload16(Ag + radv, AsB + nxt * 8192 + 4096);
            gload16(Bg, BsB + nxt * 8192);
            gload16(Bg + radv, BsB + nxt * 8192 + 4096);
            Ag += 64; Bg += 64;
        }
#else
    int srow = tid >> 1;
    int sk = (tid & 1) * 16;
    const bf16* Ap = A  + (size_t)(m0 + srow) * K + sk;
    const bf16* Bp = Bt + (size_t)(n0 + srow) * K + sk;
    // prologue: tile 0 -> buf 0
    {
        uint4 a0 = *(const uint4*)(Ap);
        uint4 a1 = *(const uint4*)(Ap + 8);
        uint4 b0 = *(const uint4*)(Bp);
        uint4 b1 = *(const uint4*)(Bp + 8);
        *(uint4*)&As[0][srow][sk]     = a0;
        *(uint4*)&As[0][srow][sk + 8] = a1;
        *(uint4*)&Bs[0][srow][sk]     = b0;
        *(uint4*)&Bs[0][srow][sk + 8] = b1;
    }
    __syncthreads();
    int cur = 0;
    for (int k0 = 0; k0 < K; k0 += 32) {
        int nxt = cur ^ 1;
        uint4 a0, a1, b0, b1;
        if (k0 + 32 < K) {
            a0 = *(const uint4*)(Ap + k0 + 32);
            a1 = *(const uint4*)(Ap + k0 + 40);
            b0 = *(const uint4*)(Bp + k0 + 32);
            b1 = *(const uint4*)(Bp + k0 + 40);
        }
#endif
        bf16x8 af[4], bf_[4];
#pragma unroll
        for (int i = 0; i < 4; ++i) {
            af[i]  = *(const bf16x8*)&As[cur][wm + i * 16 + l16][quad * 8];
            bf_[i] = *(const bf16x8*)&Bs[cur][wn + i * 16 + l16][quad * 8];
        }
#pragma unroll
        for (int mi = 0; mi < 4; ++mi)
#pragma unroll
            for (int ni = 0; ni < 4; ++ni)
                acc[mi][ni] = __builtin_amdgcn_mfma_f32_16x16x32_bf16(
                    af[mi], bf_[ni], acc[mi][ni], 0, 0, 0);
#if !HAVE_GLL
        if (k0 + 32 < K) {
            *(uint4*)&As[nxt][srow][sk]     = a0;
            *(uint4*)&As[nxt][srow][sk + 8] = a1;
            *(uint4*)&Bs[nxt][srow][sk]     = b0;
            *(uint4*)&Bs[nxt][srow][sk + 8] = b1;
        }
#endif
        __syncthreads();   // next-tile staging drained/visible; cur reads done
        cur = nxt;
    }

    float bv[4] = {0.f, 0.f, 0.f, 0.f};
    if (!OUT_BF16 && bias) {
#pragma unroll
        for (int ni = 0; ni < 4; ++ni) bv[ni] = bias[n0 + wn + ni * 16 + l16];
    }
#pragma unroll
    for (int mi = 0; mi < 4; ++mi)
#pragma unroll
        for (int reg = 0; reg < 4; ++reg) {
            size_t row = m0 + wm + mi * 16 + quad * 4 + reg;
#pragma unroll
            for (int ni = 0; ni < 4; ++ni) {
                int col = n0 + wn + ni * 16 + l16;
                float val = acc[mi][ni][reg] + bv[ni];
                if (OUT_BF16)
                    ((bf16*)Cv)[row * Nn + col] = __float2bfloat16(val);
                else
                    ((float*)Cv)[row * Nn + col] = val;
            }
        }
}

// --------------------------------------- MFMA flash attention (S^T form, dual q-group)
// QBLK=128 per block, 256 threads: each wave owns TWO independent 16-row q-groups
// (A: m0+wave*16, B: m0+64+wave*16). K/V staging, barriers, and K/V fragment reads
// are SHARED by both groups (per-q-row staging cost halves; QK^T ds_read:MFMA goes
// 8:8 -> 8:16). The two softmax/PV dependency chains are independent -> in-wave ILP
// fills the latency stalls (T15 mechanism, no extra sync).
// rpb: loaded at iteration TOP (before the K gll prefetch, so consuming it waits
// vmcnt(4), leaving the prefetch in flight); QK^T phase covers the L2 latency.
// Grid 768 = exactly 3 blocks/CU, single balanced round. LDS 53,248 -> 3 blocks/CU.
// qkv: [ROWS, 2304] bf16. rpb: [NHEAD, NSEQ, NSEQ] fp32. outb: [ROWS, DIMM] bf16.
#define KTILEB (64 * 3 * DIMM * 2)   // bytes per 64-row k-tile step in qkv
#define NBLK   (BATCH * NHEAD * (NSEQ / 128))   // 768

__global__ __launch_bounds__(256, 3) void attn_mfma(const bf16* __restrict__ qkv,
                                                    const float* __restrict__ rpb,
                                                    bf16* __restrict__ outb) {
    __shared__ char KsRaw[2][8192];      // [buf][t*2048 + s*1024 + (quad*16+l16)*16]
    __shared__ unsigned Vt32[2][64][36]; // [buf][d][k-pair dword], XOR-swizzled blocks
    __shared__ bf16 Ps[4][2][16][72];    // per-wave, per-group P (A-layout)

    int tid = threadIdx.x;
    int wave = tid >> 6, lane = tid & 63, quad = lane >> 4, l16 = lane & 15;

    // Locality-ordered bijective XCD swizzle (NBLK=768, 768%8==0):
    // 8 consecutive wids share one (h,b) K/V stripe; head rpb mostly per-XCD.
    int p   = blockIdx.x;
    int wid = (p & 7) * (NBLK / 8) + (p >> 3);
    int h   = wid >> 6;          // wid / 64
    int rem = wid & 63;
    int b   = rem >> 3;
    int mt  = rem & 7;
    int m0  = mt * 128;

    // Q fragments for both groups (wave owns rows m0+wave*16.. and m0+64+wave*16..)
    const bf16* qrowA = qkv + (size_t)(b * NSEQ + m0 + wave * 16 + l16) * (3 * DIMM) + h * DHEAD;
    const bf16* qrowB = qrowA + (size_t)64 * (3 * DIMM);
    bf16x8 qfA0 = *(const bf16x8*)(qrowA + quad * 8);
    bf16x8 qfA1 = *(const bf16x8*)(qrowA + 32 + quad * 8);
    bf16x8 qfB0 = *(const bf16x8*)(qrowB + quad * 8);
    bf16x8 qfB1 = *(const bf16x8*)(qrowB + 32 + quad * 8);

    // rpb rows for both groups (lane's q = l16)
    const float* rpA = rpb + ((size_t)h * NSEQ + (m0 + wave * 16 + l16)) * NSEQ;
    const float* rpB = rpA + (size_t)64 * NSEQ;

#if HAVE_GLL
    // K staging: wave w stages k-subtile t=w, rows w*16+l16, col chunk quad*8 (+i*32)
    const char* kgl = (const char*)(qkv + (size_t)(b * NSEQ + wave * 16 + l16) * (3 * DIMM)
                                    + DIMM + h * DHEAD + quad * 8);
    char* kdst = &KsRaw[0][0] + tid * 16 + wave * 1024;   // +buf*8192, +i*1024
#else
    int ksr = tid >> 2, ksd = (tid & 3) * 16;
    const bf16* kgf = qkv + (size_t)(b * NSEQ + ksr) * (3 * DIMM) + DIMM + h * DHEAD + ksd;
#endif

    // V loader: thread owns 2 adjacent k-rows x 8 d-cols
    int vk = (tid >> 3) * 2;            // 0..62 even
    int vd = (tid & 7) * 8;             // 0..56
    int vkp = tid >> 3;                 // logical dword col (k-pair)
    const bf16* vg = qkv + (size_t)(b * NSEQ + vk) * (3 * DIMM) + 2 * DIMM + h * DHEAD + vd;
    int wblk = (((vkp >> 2) ^ (vd >> 3)) << 2) | (vkp & 3);

    float mA = -INFINITY, lA = 0.f;
    float mB = -INFINITY, lB = 0.f;
    f32x4 accoA[4] = {}, accoB[4] = {};

    // ---------------- preload tile 0
#if HAVE_GLL
    gload16(kgl, kdst);
    gload16(kgl + 64, kdst + 1024);
#endif
    uint4 va = *(const uint4*)(vg);
    uint4 vb = *(const uint4*)(vg + 3 * DIMM);
#if !HAVE_GLL
    {
        uint4 k0v = *(const uint4*)(kgf);
        uint4 k1v = *(const uint4*)(kgf + 8);
        char* d0 = &KsRaw[0][0] + (ksr >> 4) * 2048 + (ksd >> 5) * 1024 + ((((ksd >> 3) & 3) * 16 + (ksr & 15)) * 16);
        *(uint4*)d0 = k0v;
        char* d1 = &KsRaw[0][0] + (ksr >> 4) * 2048 + ((ksd + 8) >> 5) * 1024 + (((((ksd + 8) >> 3) & 3) * 16 + (ksr & 15)) * 16);
        *(uint4*)d1 = k1v;
    }
#endif
    {
        union { uint4 q; unsigned short u[8]; } A_, B_;
        A_.q = va; B_.q = vb;
#pragma unroll
        for (int j = 0; j < 8; ++j)
            Vt32[0][vd + j][wblk] = (unsigned)A_.u[j] | ((unsigned)B_.u[j] << 16);
    }
    __syncthreads();   // drains gll vmcnt + ds writes

    for (int kt = 0; kt < 16; ++kt) {
        int cur = kt & 1, nxt = cur ^ 1;

        // ---- rpb for CURRENT tile, both groups — issued FIRST so the later
        // K-gll prefetch is not drained when these are consumed (vmcnt(4) wait).
        float4 rvA[4], rvB[4];
        {
            const float* rka = rpA + kt * 64;
            const float* rkb = rpB + kt * 64;
#pragma unroll
            for (int t = 0; t < 4; ++t) {
                rvA[t] = *(const float4*)&rka[t * 16 + quad * 4];
                rvB[t] = *(const float4*)&rkb[t * 16 + quad * 4];
            }
        }

        // ---- prefetch next tile (K -> LDS[nxt] async, V -> regs)
        if (kt + 1 < 16) {
#if HAVE_GLL
            const char* kg2 = kgl + (size_t)(kt + 1) * KTILEB;
            gload16(kg2, kdst + nxt * 8192);
            gload16(kg2 + 64, kdst + nxt * 8192 + 1024);
#endif
            const bf16* v2 = vg + (size_t)(kt + 1) * 64 * (3 * DIMM);
            va = *(const uint4*)(v2);
            vb = *(const uint4*)(v2 + 3 * DIMM);
        }

        // ---- S^T = K Q^T for both groups (K fragments shared)
        f32x4 accsA[4] = {}, accsB[4] = {};
        __builtin_amdgcn_s_setprio(1);
#pragma unroll
        for (int t = 0; t < 4; ++t) {
            const char* kb = &KsRaw[cur][0] + t * 2048 + (quad * 16 + l16) * 16;
            bf16x8 kf0 = *(const bf16x8*)(kb);
            bf16x8 kf1 = *(const bf16x8*)(kb + 1024);
            accsA[t] = __builtin_amdgcn_mfma_f32_16x16x32_bf16(kf0, qfA0, accsA[t], 0, 0, 0);
            accsA[t] = __builtin_amdgcn_mfma_f32_16x16x32_bf16(kf1, qfA1, accsA[t], 0, 0, 0);
            accsB[t] = __builtin_amdgcn_mfma_f32_16x16x32_bf16(kf0, qfB0, accsB[t], 0, 0, 0);
            accsB[t] = __builtin_amdgcn_mfma_f32_16x16x32_bf16(kf1, qfB1, accsB[t], 0, 0, 0);
        }
        __builtin_amdgcn_s_setprio(0);

        // ---- softmax, two independent chains (compiler interleaves for ILP)
        float mxA = -INFINITY, mxB = -INFINITY;
        {
            float rbA[4][4] = {{rvA[0].x, rvA[0].y, rvA[0].z, rvA[0].w},
                               {rvA[1].x, rvA[1].y, rvA[1].z, rvA[1].w},
                               {rvA[2].x, rvA[2].y, rvA[2].z, rvA[2].w},
                               {rvA[3].x, rvA[3].y, rvA[3].z, rvA[3].w}};
            float rbB[4][4] = {{rvB[0].x, rvB[0].y, rvB[0].z, rvB[0].w},
                               {rvB[1].x, rvB[1].y, rvB[1].z, rvB[1].w},
                               {rvB[2].x, rvB[2].y, rvB[2].z, rvB[2].w},
                               {rvB[3].x, rvB[3].y, rvB[3].z, rvB[3].w}};
#pragma unroll
            for (int t = 0; t < 4; ++t)
#pragma unroll
                for (int r = 0; r < 4; ++r) {
                    accsA[t][r] = fmaf(accsA[t][r], SCALE, rbA[t][r]);
                    mxA = fmaxf(mxA, accsA[t][r]);
                    accsB[t][r] = fmaf(accsB[t][r], SCALE, rbB[t][r]);
                    mxB = fmaxf(mxB, accsB[t][r]);
                }
        }
        mxA = fmaxf(mxA, __shfl_xor(mxA, 16));
        mxA = fmaxf(mxA, __shfl_xor(mxA, 32));
        mxB = fmaxf(mxB, __shfl_xor(mxB, 16));
        mxB = fmaxf(mxB, __shfl_xor(mxB, 32));

        // ---- T13 defer-rescale per group (wave-uniform; ~never taken)
        if (__any(mxA > mA + 8.0f)) {
            float mn = fmaxf(mA, mxA);
            float alpha = __expf(mA - mn);
            mA = mn;
            lA *= alpha;
            float ab[4];
#pragma unroll
            for (int r = 0; r < 4; ++r) ab[r] = __shfl(alpha, quad * 4 + r);
#pragma unroll
            for (int dt = 0; dt < 4; ++dt)
#pragma unroll
                for (int r = 0; r < 4; ++r) accoA[dt][r] *= ab[r];
        }
        if (__any(mxB > mB + 8.0f)) {
            float mn = fmaxf(mB, mxB);
            float alpha = __expf(mB - mn);
            mB = mn;
            lB *= alpha;
            float ab[4];
#pragma unroll
            for (int r = 0; r < 4; ++r) ab[r] = __shfl(alpha, quad * 4 + r);
#pragma unroll
            for (int dt = 0; dt < 4; ++dt)
#pragma unroll
                for (int r = 0; r < 4; ++r) accoB[dt][r] *= ab[r];
        }

        float sumA = 0.f, sumB = 0.f;
#pragma unroll
        for (int t = 0; t < 4; ++t)
#pragma unroll
            for (int r = 0; r < 4; ++r) {
                float pa = __expf(accsA[t][r] - mA);
                accsA[t][r] = pa;
                sumA += pa;
                float pb = __expf(accsB[t][r] - mB);
                accsB[t][r] = pb;
                sumB += pb;
            }
        sumA += __shfl_xor(sumA, 16);
        sumA += __shfl_xor(sumA, 32);
        sumB += __shfl_xor(sumB, 16);
        sumB += __shfl_xor(sumB, 32);
        lA += sumA;
        lB += sumB;

        // ---- P^T -> Ps for both groups (A-layout: row q=l16, cols k)
#pragma unroll
        for (int t = 0; t < 4; ++t) {
            uint2 wA, wB;
            wA.x = pk2(accsA[t][0], accsA[t][1]);
            wA.y = pk2(accsA[t][2], accsA[t][3]);
            wB.x = pk2(accsB[t][0], accsB[t][1]);
            wB.y = pk2(accsB[t][2], accsB[t][3]);
            *(uint2*)&Ps[wave][0][l16][t * 16 + quad * 4] = wA;
            *(uint2*)&Ps[wave][1][l16][t * 16 + quad * 4] = wB;
        }
        __asm__ volatile("s_waitcnt lgkmcnt(0)" ::: "memory");

        // ---- O += P V for both groups (V fragments shared)
        __builtin_amdgcn_s_setprio(1);
#pragma unroll
        for (int s = 0; s < 2; ++s) {
            bf16x8 pfA = *(const bf16x8*)&Ps[wave][0][l16][s * 32 + quad * 8];
            bf16x8 pfB = *(const bf16x8*)&Ps[wave][1][l16][s * 32 + quad * 8];
#pragma unroll
            for (int dt = 0; dt < 4; ++dt) {
                int row = dt * 16 + l16;
                int sblk = (((s * 4 + quad) ^ ((row >> 3) & 7)) << 2);
                bf16x8 vf = *(const bf16x8*)&Vt32[cur][row][sblk];
                accoA[dt] = __builtin_amdgcn_mfma_f32_16x16x32_bf16(pfA, vf, accoA[dt], 0, 0, 0);
                accoB[dt] = __builtin_amdgcn_mfma_f32_16x16x32_bf16(pfB, vf, accoB[dt], 0, 0, 0);
            }
        }
        __builtin_amdgcn_s_setprio(0);

        // ---- stage prefetched V into Vt[nxt]
        if (kt + 1 < 16) {
            union { uint4 q; unsigned short u[8]; } A_, B_;
            A_.q = va; B_.q = vb;
#pragma unroll
            for (int j = 0; j < 8; ++j)
                Vt32[nxt][vd + j][wblk] = (unsigned)A_.u[j] | ((unsigned)B_.u[j] << 16);
        }
        __syncthreads();   // K[nxt] gll drained; V[nxt] visible; cur reads done
    }

    // ---- epilogue: O / l for both groups, bf16 store
    float invlA[4], invlB[4];
#pragma unroll
    for (int r = 0; r < 4; ++r) {
        invlA[r] = 1.f / __shfl(lA, quad * 4 + r);
        invlB[r] = 1.f / __shfl(lB, quad * 4 + r);
    }
    bf16* orowA = outb + (size_t)(b * NSEQ + m0 + wave * 16) * DIMM + h * DHEAD;
    bf16* orowB = orowA + (size_t)64 * DIMM;
#pragma unroll
    for (int dt = 0; dt < 4; ++dt)
#pragma unroll
        for (int r = 0; r < 4; ++r) {
            orowA[(size_t)(quad * 4 + r) * DIMM + dt * 16 + l16] =
                __float2bfloat16(accoA[dt][r] * invlA[r]);
            orowB[(size_t)(quad * 4 + r) * DIMM + dt * 16 + l16] =
                __float2bfloat16(accoB[dt][r] * invlB[r]);
        }
}

// ---------------------------------------------------------------- launch
extern "C" void kernel_launch(void* const* d_in, const int* in_sizes, int n_in,
                              void* d_out, int out_size, void* d_ws, size_t ws_size,
                              hipStream_t stream) {
    const float* x     = (const float*)d_in[0];
    const float* rpb   = (const float*)d_in[1];
    const float* W_qkv = (const float*)d_in[2];
    const float* W_out = (const float*)d_in[3];
    const float* b_out = (const float*)d_in[4];
    const float* ln_g  = (const float*)d_in[5];
    const float* ln_b  = (const float*)d_in[6];
    float* out = (float*)d_out;

    char* p = (char*)d_ws;
    bf16* xn    = (bf16*)p; p += (size_t)ROWS * DIMM * 2;
    bf16* qkv   = (bf16*)p; p += (size_t)ROWS * 3 * DIMM * 2;
    bf16* attn  = (bf16*)p; p += (size_t)ROWS * DIMM * 2;
    bf16* WqkvT = (bf16*)p; p += (size_t)3 * DIMM * DIMM * 2;
    bf16* WoutT = (bf16*)p; p += (size_t)DIMM * DIMM * 2;

    prep_kernel<<<ROWS + NT_QKV + NT_OUT, 256, 0, stream>>>(
        x, ln_g, ln_b, xn, W_qkv, WqkvT, W_out, WoutT);

    gemm_mfma<true><<<dim3(3 * DIMM / 128, ROWS / 128), 256, 0, stream>>>(
        xn, WqkvT, nullptr, qkv, ROWS, 3 * DIMM, DIMM);

    attn_mfma<<<NBLK, 256, 0, stream>>>(qkv, rpb, attn);

    gemm_mfma<false><<<dim3(DIMM / 128, ROWS / 128), 256, 0, stream>>>(
        attn, WoutT, b_out, out, ROWS, DIMM, DIMM);
}